// Round 2
// baseline (169.892 us; speedup 1.0000x reference)
//
#include <hip/hip_runtime.h>
#include <math.h>

#define F 128
#define OUT 128

typedef unsigned short ushort_t;
typedef __attribute__((ext_vector_type(8))) short bfrag;   // 8 bf16
typedef __attribute__((ext_vector_type(4))) float ffrag;   // 4 fp32 acc

__device__ __forceinline__ float bf_lo(unsigned int u) {
    return __uint_as_float(u << 16);
}
__device__ __forceinline__ float bf_hi(unsigned int u) {
    return __uint_as_float(u & 0xffff0000u);
}
__device__ __forceinline__ ushort_t f2bf(float f) {
    unsigned int x = __float_as_uint(f);
    unsigned int r = x + 0x7fffu + ((x >> 16) & 1u);
    return (ushort_t)(r >> 16);
}
__device__ __forceinline__ unsigned pk2(float lo, float hi) {
    return (unsigned)f2bf(lo) | ((unsigned)f2bf(hi) << 16);
}

// DPP rotate-add within a 16-lane row (VALU, no LDS pipe).
// row_ror:N ctrl = 0x120+N. Double-evaluates x: use with plain lvalues only.
#define DPP_ADD(x, ctrl) \
    ((x) + __int_as_float(__builtin_amdgcn_update_dpp( \
        0, __float_as_int(x), (ctrl), 0xf, 0xf, true)))

// ---------------------------------------------------------------------------
// prep: heterogeneous grid.
//  part0: feat fp32 -> abig[:, :128] bf16 + srcpack feat-half (interleaved:
//         feature f at (f>>2)*8 + 4 + (f&3)).  All vector stores.
//  part1: btp[j*128+k] = bf16(B[k][j]), B = [w1[:F] | w1[F:]] cols j=0..255.
//  part2: btf[j*256+k] = bf16(wf[k][j]), j=0..127.
//  part3: rowptr (dst sorted).
// ---------------------------------------------------------------------------
__global__ __launch_bounds__(256) void prep_kernel(
    const float* __restrict__ feat, const float* __restrict__ w1,
    const float* __restrict__ wf, const int* __restrict__ dst,
    ushort_t* __restrict__ abig, ushort_t* __restrict__ srcpack,
    ushort_t* __restrict__ btp, ushort_t* __restrict__ btf,
    int* __restrict__ row_ptr, int n, int e, int nb0, int nb1, int nb2)
{
    const int b = blockIdx.x, t = threadIdx.x;
    if (b < nb0) {
        int i = b * 256 + t;
        if (i >= n * 16) return;
        int row = i >> 4, c = (i & 15) * 8;
        float4 a = *(const float4*)(feat + (size_t)row * F + c);
        float4 bb = *(const float4*)(feat + (size_t)row * F + c + 4);
        unsigned p0 = pk2(a.x, a.y), p1 = pk2(a.z, a.w);
        unsigned p2 = pk2(bb.x, bb.y), p3 = pk2(bb.z, bb.w);
        *(uint4*)(abig + (size_t)row * 256 + c) = make_uint4(p0, p1, p2, p3);
        *(uint2*)(srcpack + (size_t)row * 256 + c * 2 + 4) = make_uint2(p0, p1);
        *(uint2*)(srcpack + (size_t)row * 256 + c * 2 + 12) = make_uint2(p2, p3);
    } else if (b < nb0 + nb1) {
        int idx = (b - nb0) * 256 + t;                 // 0..32767
        int j = idx >> 7, k = idx & 127;
        float v = (j < F) ? w1[(size_t)k * F + j]
                          : w1[(size_t)(F + k) * F + (j - F)];
        btp[idx] = f2bf(v);
    } else if (b < nb0 + nb1 + nb2) {
        int idx = (b - nb0 - nb1) * 256 + t;           // 0..32767
        int j = idx >> 8, k = idx & 255;
        btf[idx] = f2bf(wf[(size_t)k * F + j]);
    } else {
        int i = (b - nb0 - nb1 - nb2) * 256 + t;
        if (i >= e) return;
        int d = dst[i];
        int prev = (i == 0) ? -1 : dst[i - 1];
        for (int v = prev + 1; v <= d; ++v) row_ptr[v] = i;
        if (i == e - 1) {
            for (int v = d + 1; v <= n; ++v) row_ptr[v] = e;
        }
    }
}

// ---------------------------------------------------------------------------
// G1 (proj): C[n x 256] = abig_feat(bf16) @ btp, epilogue exp(2*(c+bias)).
// Block = 64 rows x 256 cols, 4 waves (wave w: cols 64w..64w+63).
// B-fragments hoisted to registers before K-loop (no global in MFMA loop).
// Epilogue: LDS transpose per wave -> coalesced uint4/uint2 stores.
// cols<128 -> e_dst (+b1); cols>=128 -> srcpack e_src half (interleaved).
// ---------------------------------------------------------------------------
#define PST 136
__global__ __launch_bounds__(256) void proj_gemm_kernel(
    const ushort_t* __restrict__ abig, const ushort_t* __restrict__ btp,
    const float* __restrict__ b1, ushort_t* __restrict__ e_dst,
    ushort_t* __restrict__ srcpack, int n)
{
    __shared__ ushort_t As[64 * PST];        // 17408 B
    __shared__ ushort_t Ep[4][16 * 80];      // 10240 B
    const int t = threadIdx.x;
    const int wv = t >> 6, lane = t & 63;
    const int lm = lane & 15, quad = lane >> 4;
    const int row0 = blockIdx.x * 64, col0 = wv * 64;

#pragma unroll
    for (int k = 0; k < 4; ++k) {            // 64 rows x 16 uint4, coalesced
        int l = k * 256 + t;
        int r = l >> 4, ch = l & 15;
        uint4 d = make_uint4(0, 0, 0, 0);
        if (row0 + r < n) d = *(const uint4*)(abig + (size_t)(row0 + r) * 256 + ch * 8);
        *(uint4*)(As + r * PST + ch * 8) = d;
    }
    __syncthreads();

    bfrag bfr[4][4];
#pragma unroll
    for (int ks = 0; ks < 4; ++ks)
#pragma unroll
        for (int ni = 0; ni < 4; ++ni)
            bfr[ks][ni] = *(const bfrag*)(btp + (size_t)(col0 + ni * 16 + lm) * 128
                                          + ks * 32 + quad * 8);

    ffrag acc[4][4];
#pragma unroll
    for (int mi = 0; mi < 4; ++mi)
#pragma unroll
        for (int ni = 0; ni < 4; ++ni) acc[mi][ni] = (ffrag){0.f, 0.f, 0.f, 0.f};

#pragma unroll
    for (int ks = 0; ks < 4; ++ks)
#pragma unroll
        for (int mi = 0; mi < 4; ++mi) {
            bfrag af = *(const bfrag*)(As + (mi * 16 + lm) * PST + ks * 32 + quad * 8);
#pragma unroll
            for (int ni = 0; ni < 4; ++ni)
                acc[mi][ni] = __builtin_amdgcn_mfma_f32_16x16x32_bf16(
                    af, bfr[ks][ni], acc[mi][ni], 0, 0, 0);
        }

    float bias[4];
#pragma unroll
    for (int ni = 0; ni < 4; ++ni)
        bias[ni] = (col0 < F) ? b1[col0 + ni * 16 + lm] : 0.f;

#pragma unroll
    for (int mi = 0; mi < 4; ++mi) {
        // compute-layout write into per-wave patch (conflict-free)
#pragma unroll
        for (int ni = 0; ni < 4; ++ni)
#pragma unroll
            for (int r = 0; r < 4; ++r)
                Ep[wv][(quad * 4 + r) * 80 + ni * 16 + lm] =
                    f2bf(__expf(2.f * (acc[mi][ni][r] + bias[ni])));
        // coalesced read-out: 2 passes x 8 rows x 8 lanes x 16B
#pragma unroll
        for (int ps = 0; ps < 2; ++ps) {
            int rl = ps * 8 + (lane >> 3), co = (lane & 7) * 8;
            uint4 vv = *(const uint4*)(&Ep[wv][rl * 80 + co]);
            int grow = row0 + mi * 16 + rl;
            if (grow < n) {
                if (col0 < F) {
                    *(uint4*)(e_dst + (size_t)grow * F + col0 + co) = vv;
                } else {
                    int f0 = col0 - F + co;   // multiple of 8
                    *(uint2*)(srcpack + (size_t)grow * 256 + f0 * 2) =
                        make_uint2(vv.x, vv.y);
                    *(uint2*)(srcpack + (size_t)grow * 256 + f0 * 2 + 8) =
                        make_uint2(vv.z, vv.w);
                }
            }
        }
    }
}

// ---------------------------------------------------------------------------
// K2: fused score+softmax+aggregate. One 32-lane half-wave per node; one
// uint4 gather per edge gives 4 e_src + 4 feat bf16 per lane. Static softmax
// bound M = b2 + sum|w2|; 4-edge ILP with software prefetch of the NEXT
// 4-edge gather block (hides LLC latency under compute).  Per-edge reduce:
// 4x DPP row_ror adds (VALU) + one xor-16 swizzle (was 5 swizzles).
// srcpack row = 256 ushort = 512 B = 32 uint4  ->  lane-base ptr stride 32.
// Writes neigh bf16 to abig[:, 128:].
// ---------------------------------------------------------------------------
__global__ __launch_bounds__(256) void fused_kernel(
    const ushort_t* __restrict__ e_dst, const ushort_t* __restrict__ srcpack,
    const int* __restrict__ src, const int* __restrict__ row_ptr,
    const float* __restrict__ w2, ushort_t* __restrict__ abig, int n)
{
    const int v = (int)((blockIdx.x * 256u + threadIdx.x) >> 5);
    const int fl = threadIdx.x & 31;
    const int sbase = threadIdx.x & 32;

    const float4 wv4 = ((const float4*)w2)[fl];
    const float w0 = wv4.x, w1_ = wv4.y, w2_ = wv4.z, w3_ = wv4.w;
    float sw = w0 + w1_ + w2_ + w3_;
    float aw = fabsf(w0) + fabsf(w1_) + fabsf(w2_) + fabsf(w3_);
#pragma unroll
    for (int off = 16; off; off >>= 1) {
        sw += __shfl_xor(sw, off, 64);
        aw += __shfl_xor(aw, off, 64);
    }
    const float K = sw - aw;           // score - M = K - 2*pv  (always <= 0)
    const float L2E = 1.4426950408889634f;
    const float K2 = K * L2E;          // g = exp2(K2 - 2*L2E*p)

    if (v >= n) return;
    const int begin = row_ptr[v], end = row_ptr[v + 1];

    const uint2 ud = *(const uint2*)(e_dst + (size_t)v * F + fl * 4);
    const float ea0 = bf_lo(ud.x), ea1 = bf_hi(ud.x);
    const float ea2 = bf_lo(ud.y), ea3 = bf_hi(ud.y);

    const uint4* __restrict__ sp = (const uint4*)srcpack + fl;  // lane base

    float s = 0.f, a0 = 0.f, a1 = 0.f, a2 = 0.f, a3 = 0.f;

    for (int cb = begin; cb < end; cb += 32) {
        const int clen = min(32, end - cb);
        const int sv = (fl < clen) ? src[cb + fl] : 0;
        int jj = 0;
        uint4 u[4];
        if (jj + 4 <= clen) {
#pragma unroll
            for (int q = 0; q < 4; ++q) {
                const int sq = __shfl(sv, sbase + q, 64);
                u[q] = sp[(size_t)sq * 32];
            }
        }
        while (jj + 4 <= clen) {
            const int jn = jj + 4;
            uint4 un[4];
            if (jn + 4 <= clen) {            // prefetch next block
#pragma unroll
                for (int q = 0; q < 4; ++q) {
                    const int sq = __shfl(sv, sbase + jn + q, 64);
                    un[q] = sp[(size_t)sq * 32];
                }
            }
            float p[4];
#pragma unroll
            for (int q = 0; q < 4; ++q) {
                float r;
                r = __builtin_amdgcn_rcpf(fmaf(ea0, bf_lo(u[q].x), 1.f)); p[q] = w0 * r;
                r = __builtin_amdgcn_rcpf(fmaf(ea1, bf_hi(u[q].x), 1.f)); p[q] = fmaf(w1_, r, p[q]);
                r = __builtin_amdgcn_rcpf(fmaf(ea2, bf_lo(u[q].y), 1.f)); p[q] = fmaf(w2_, r, p[q]);
                r = __builtin_amdgcn_rcpf(fmaf(ea3, bf_hi(u[q].y), 1.f)); p[q] = fmaf(w3_, r, p[q]);
            }
#pragma unroll
            for (int q = 0; q < 4; ++q) {
                p[q] = DPP_ADD(p[q], 0x121);     // row_ror:1
                p[q] = DPP_ADD(p[q], 0x122);     // row_ror:2
                p[q] = DPP_ADD(p[q], 0x124);     // row_ror:4
                p[q] = DPP_ADD(p[q], 0x128);     // row_ror:8
                p[q] += __shfl_xor(p[q], 16, 64);
            }
            float g[4];
#pragma unroll
            for (int q = 0; q < 4; ++q)
                g[q] = exp2f(fmaf(-2.f * L2E, p[q], K2));
            s += (g[0] + g[1]) + (g[2] + g[3]);
#pragma unroll
            for (int q = 0; q < 4; ++q) {
                a0 = fmaf(g[q], bf_lo(u[q].z), a0);
                a1 = fmaf(g[q], bf_hi(u[q].z), a1);
                a2 = fmaf(g[q], bf_lo(u[q].w), a2);
                a3 = fmaf(g[q], bf_hi(u[q].w), a3);
            }
            jj = jn;
            if (jj + 4 <= clen) {
#pragma unroll
                for (int q = 0; q < 4; ++q) u[q] = un[q];
            }
        }
        for (; jj < clen; ++jj) {
            const int s0 = __shfl(sv, sbase + jj, 64);
            const uint4 u0 = sp[(size_t)s0 * 32];
            float r, p0;
            r = __builtin_amdgcn_rcpf(fmaf(ea0, bf_lo(u0.x), 1.f)); p0 = w0 * r;
            r = __builtin_amdgcn_rcpf(fmaf(ea1, bf_hi(u0.x), 1.f)); p0 = fmaf(w1_, r, p0);
            r = __builtin_amdgcn_rcpf(fmaf(ea2, bf_lo(u0.y), 1.f)); p0 = fmaf(w2_, r, p0);
            r = __builtin_amdgcn_rcpf(fmaf(ea3, bf_hi(u0.y), 1.f)); p0 = fmaf(w3_, r, p0);
            p0 = DPP_ADD(p0, 0x121);
            p0 = DPP_ADD(p0, 0x122);
            p0 = DPP_ADD(p0, 0x124);
            p0 = DPP_ADD(p0, 0x128);
            p0 += __shfl_xor(p0, 16, 64);
            const float g0 = exp2f(fmaf(-2.f * L2E, p0, K2));
            s += g0;
            a0 = fmaf(g0, bf_lo(u0.z), a0);
            a1 = fmaf(g0, bf_hi(u0.z), a1);
            a2 = fmaf(g0, bf_lo(u0.w), a2);
            a3 = fmaf(g0, bf_hi(u0.w), a3);
        }
    }

    const float inv = (end > begin) ? 1.f / s : 0.f;
    ushort4 o = make_ushort4(f2bf(a0 * inv), f2bf(a1 * inv),
                             f2bf(a2 * inv), f2bf(a3 * inv));
    *(ushort4*)(abig + (size_t)v * 256 + 128 + fl * 4) = o;
}

// ---------------------------------------------------------------------------
// G2 (out): out[n x 128] = abig(bf16, K=256) @ btf + bf.
// Block = 64 rows x 128 cols, 4 waves (wave w: cols 32w..32w+31).
// B-fragments hoisted; fp32 output stores are naturally coalesced.
// ---------------------------------------------------------------------------
#define OST 280
__global__ __launch_bounds__(256) void out_gemm_kernel(
    const ushort_t* __restrict__ abig, const ushort_t* __restrict__ btf,
    const float* __restrict__ bfv, float* __restrict__ out, int n)
{
    __shared__ ushort_t As[64 * OST];        // 35840 B
    const int t = threadIdx.x;
    const int wv = t >> 6, lane = t & 63;
    const int lm = lane & 15, quad = lane >> 4;
    const int row0 = blockIdx.x * 64, col0 = wv * 32;

#pragma unroll
    for (int k = 0; k < 8; ++k) {            // 64 rows x 32 uint4, coalesced
        int l = k * 256 + t;
        int r = l >> 5, ch = l & 31;
        uint4 d = make_uint4(0, 0, 0, 0);
        if (row0 + r < n) d = *(const uint4*)(abig + (size_t)(row0 + r) * 256 + ch * 8);
        *(uint4*)(As + r * OST + ch * 8) = d;
    }
    __syncthreads();

    bfrag bfr[8][2];
#pragma unroll
    for (int ks = 0; ks < 8; ++ks)
#pragma unroll
        for (int ni = 0; ni < 2; ++ni)
            bfr[ks][ni] = *(const bfrag*)(btf + (size_t)(col0 + ni * 16 + lm) * 256
                                          + ks * 32 + quad * 8);

    ffrag acc[4][2];
#pragma unroll
    for (int mi = 0; mi < 4; ++mi)
#pragma unroll
        for (int ni = 0; ni < 2; ++ni) acc[mi][ni] = (ffrag){0.f, 0.f, 0.f, 0.f};

#pragma unroll
    for (int ks = 0; ks < 8; ++ks)
#pragma unroll
        for (int mi = 0; mi < 4; ++mi) {
            bfrag af = *(const bfrag*)(As + (mi * 16 + lm) * OST + ks * 32 + quad * 8);
#pragma unroll
            for (int ni = 0; ni < 2; ++ni)
                acc[mi][ni] = __builtin_amdgcn_mfma_f32_16x16x32_bf16(
                    af, bfr[ks][ni], acc[mi][ni], 0, 0, 0);
        }

#pragma unroll
    for (int ni = 0; ni < 2; ++ni) {
        const int j = col0 + ni * 16 + lm;
        const float bb = bfv[j];
#pragma unroll
        for (int mi = 0; mi < 4; ++mi)
#pragma unroll
            for (int r = 0; r < 4; ++r) {
                int grow = row0 + mi * 16 + quad * 4 + r;
                if (grow < n) out[(size_t)grow * OUT + j] = acc[mi][ni][r] + bb;
            }
    }
}

// ---------------------------------------------------------------------------
extern "C" void kernel_launch(void* const* d_in, const int* in_sizes, int n_in,
                              void* d_out, int out_size, void* d_ws, size_t ws_size,
                              hipStream_t stream)
{
    const float* feat = (const float*)d_in[0];
    const int*   src  = (const int*)d_in[1];
    const int*   dst  = (const int*)d_in[2];
    const float* w1   = (const float*)d_in[3];
    const float* b1   = (const float*)d_in[4];
    const float* w2   = (const float*)d_in[5];
    const float* b2   = (const float*)d_in[6];  (void)b2; // cancels in softmax
    const float* wf   = (const float*)d_in[7];
    const float* bfv  = (const float*)d_in[8];
    float* out = (float*)d_out;

    const int n = in_sizes[0] / F;   // 40000
    const int e = in_sizes[1];       // 640000

    ushort_t* abig    = (ushort_t*)d_ws;                   // n*256 bf16 [feat|neigh]
    ushort_t* e_dst   = abig + (size_t)n * 256;            // n*128 bf16
    ushort_t* srcpack = e_dst + (size_t)n * 128;           // n*256 bf16 interleaved
    ushort_t* btp     = srcpack + (size_t)n * 256;         // 256*128 bf16 col-major
    ushort_t* btf     = btp + 32768;                       // 128*256 bf16 col-major
    int* row_ptr      = (int*)(btf + 32768);               // n+1

    const int nb0 = (n * 16 + 255) / 256;   // 2500
    const int nb1 = 128, nb2 = 128;
    const int nb3 = (e + 255) / 256;        // 2500

    prep_kernel<<<nb0 + nb1 + nb2 + nb3, 256, 0, stream>>>(
        feat, w1, wf, dst, abig, srcpack, btp, btf, row_ptr, n, e, nb0, nb1, nb2);
    proj_gemm_kernel<<<(n + 63) / 64, 256, 0, stream>>>(
        abig, btp, b1, e_dst, srcpack, n);
    fused_kernel<<<(n + 7) / 8, 256, 0, stream>>>(
        e_dst, srcpack, src, row_ptr, w2, abig, n);
    out_gemm_kernel<<<(n + 63) / 64, 256, 0, stream>>>(abig, btf, bfv, out, n);
}